// Round 12
// baseline (277.231 us; speedup 1.0000x reference)
//
#include <hip/hip_runtime.h>
#include <hip/hip_bf16.h>

#define NT 4096   // tokens
#define DM 1024   // d_model
#define DH 4096   // d_hidden
#define NE 8      // experts

#define BM 128
#define BN 128
#define BK 32
#define MAXT 40      // max padded M-tiles
#define MAXROWS 5120 // 40*128
#define KSPL2 2      // split-K for GEMM2 (K-window 2048)
#define BKP 40       // fallback LDS pad
#define G1B (8 * 4 * MAXT)  // gemm1 block count (1280)

typedef short bf16x8 __attribute__((ext_vector_type(8)));
typedef float f32x4 __attribute__((ext_vector_type(4)));
typedef float f4 __attribute__((ext_vector_type(4)));

// meta ints at ws base
#define MI_COUNTS 0
#define MI_POFF   16
#define MI_NTILES 32
#define MI_TILEE  48
#define MI_TILER  112
#define MI_TILES0 176

#define O_BUCKET 1024ull
#define O_XB  (O_BUCKET + (size_t)NE * NT * 4)
#define O_H   (O_XB + (size_t)NT * DM * 2)                     // +8 MB
#define O_W1T (O_H + (size_t)MAXROWS * DH * 2)                 // +40 MB
#define O_W2T (O_W1T + (size_t)NE * DM * DH * 2)               // +64 MB
#define WS_NEED (O_W2T + (size_t)NE * DH * DM * 2)             // ~176 MiB
#define O_P   O_W1T   // split-K partials alias dead w1t

static __device__ __forceinline__ unsigned short f2bf(float f) {
  union { __hip_bfloat16 h; unsigned short u; } cv;
  cv.h = __float2bfloat16(f);
  return cv.u;
}

static __device__ __forceinline__ void gload16(const void* g, void* l) {
  __builtin_amdgcn_global_load_lds(
      (const __attribute__((address_space(1))) void*)g,
      (__attribute__((address_space(3))) void*)l, 16, 0, 0);
}

// ---------------------------------------------------------------------------
// Tiled weight layout: bf16 tiles [128 n'][32 k'] (8 KB, row=64B), ordered
// [e][ntile][kt] with kt fastest. Tile (e,nt,kt) elem (n',k') =
// W[e][kt*32+k'][nt*128+n']. GEMM stages one tile per K-step as a single
// linear 8 KB burst.
//
// convert_v4: one block converts a 64k x 64n region of fp32 [K][N] into the
// corresponding halves of two k-tiles. Low-VGPR (v[4] only) so a STANDALONE
// launch reaches 8 waves/SIMD (r6 showed 3.65 TB/s needs that occupancy).
// ---------------------------------------------------------------------------
static __device__ __forceinline__ void convert_v4(
    const float* __restrict__ S, __hip_bfloat16* __restrict__ D, int N,
    int KTcnt, int kglob0, int nglob0, char* smem) {
  auto Ls = reinterpret_cast<__hip_bfloat16(*)[72]>(smem);  // [64][72]
  const int tid = threadIdx.x;
  const int c4 = tid & 15, rk = tid >> 4;
  const float* src = S + (size_t)(kglob0 + rk * 4) * N + nglob0 + c4 * 4;
  f4 v[4];
#pragma unroll
  for (int j = 0; j < 4; ++j) v[j] = *(const f4*)(src + (size_t)j * N);
#pragma unroll
  for (int i = 0; i < 4; ++i) {
    ushort4 w;
    w.x = f2bf(v[0][i]); w.y = f2bf(v[1][i]);
    w.z = f2bf(v[2][i]); w.w = f2bf(v[3][i]);
    *(ushort4*)&Ls[c4 * 4 + i][rk * 4] = w;  // Ls[nl][kl..kl+3]
  }
  __syncthreads();
  const int r = tid >> 2, q = tid & 3;
  const int nt = nglob0 >> 7;
  const int npr = (nglob0 & 64) + r;  // row within the 128-row tile
#pragma unroll
  for (int u = 0; u < 2; ++u) {
    const int g = q * 2 + u;                  // k-granule 0..7 (8 k each)
    const int kt = (kglob0 >> 5) + (g >> 2);  // which k-tile
    uint4 w = *(const uint4*)&Ls[r][g * 8];
    *(uint4*)(D + ((size_t)nt * KTcnt + kt) * 4096 + npr * 32 + (g & 3) * 8) =
        w;
  }
}

// ---------------------------------------------------------------------------
// Gate wave body: 8 logits (double accum -> first-max argmax), bucket
// scatter, x -> bf16.
// ---------------------------------------------------------------------------
static __device__ __forceinline__ void gate_body(
    const float* __restrict__ x, const float* __restrict__ gw,
    const float* __restrict__ gb, int* __restrict__ counts,
    int* __restrict__ bucket, __hip_bfloat16* __restrict__ xb, int bid) {
  const int tid = threadIdx.x;
  const int wid = tid >> 6;
  const int lane = tid & 63;
  const int t = bid * 4 + wid;

  const f4* xrow = (const f4*)(x + (size_t)t * DM);
  ushort4* xbrow = (ushort4*)(xb + (size_t)t * DM);

  double part[NE];
#pragma unroll
  for (int e = 0; e < NE; ++e) part[e] = 0.0;

#pragma unroll
  for (int q = 0; q < 4; ++q) {
    f4 v = xrow[q * 64 + lane];
    ushort4 s;
    s.x = f2bf(v[0]); s.y = f2bf(v[1]); s.z = f2bf(v[2]); s.w = f2bf(v[3]);
    xbrow[q * 64 + lane] = s;
#pragma unroll
    for (int e = 0; e < NE; ++e) {
      f4 w = ((const f4*)(gw + (size_t)e * DM))[q * 64 + lane];
      part[e] += (double)v[0] * w[0] + (double)v[1] * w[1] +
                 (double)v[2] * w[2] + (double)v[3] * w[3];
    }
  }
#pragma unroll
  for (int off = 32; off; off >>= 1) {
#pragma unroll
    for (int e = 0; e < NE; ++e) part[e] += __shfl_down(part[e], off);
  }
  if (lane == 0) {
    double best = part[0] + (double)gb[0];
    int bi = 0;
#pragma unroll
    for (int e = 1; e < NE; ++e) {
      double le = part[e] + (double)gb[e];
      if (le > best) { best = le; bi = e; }
    }
    int pos = atomicAdd(&counts[bi], 1);
    bucket[bi * NT + pos] = t;
  }
}

__global__ __launch_bounds__(256) void gate_route_kernel(
    const float* __restrict__ x, const float* __restrict__ gw,
    const float* __restrict__ gb, int* __restrict__ counts,
    int* __restrict__ bucket, __hip_bfloat16* __restrict__ xb) {
  gate_body(x, gw, gb, counts, bucket, xb, blockIdx.x);
}

// ---------------------------------------------------------------------------
// cw1: STANDALONE convert of w1 -> tiled (8192 blocks of 64x64). Low VGPR,
// no gate branch -> high occupancy (the fused variants sat at 27% / 2 TB/s).
// e in low 3 bits spreads experts across XCDs; ktg fastest for sequential
// tile writes within (e,nt).
// ---------------------------------------------------------------------------
__global__ __launch_bounds__(256) void cw1_kernel(
    const float* __restrict__ w1, __hip_bfloat16* __restrict__ w1t) {
  __shared__ __align__(16) char smem[9216];
  const int id = blockIdx.x;
  const int e = id & 7;
  const int rem = id >> 3;        // 0..1023
  const int ktg = rem & 15;       // K=1024 -> 16 groups of 64
  const int m = rem >> 4;         // 0..63 (N=4096 / 64)
  convert_v4(w1 + (size_t)e * DM * DH, w1t + (size_t)e * DM * DH, DH,
             DM / 32, ktg * 64, m * 64, smem);
}

// ---------------------------------------------------------------------------
// Prefix + padded tile table + bucket padding.
// ---------------------------------------------------------------------------
__global__ void prefix_kernel(int* __restrict__ meta, int* __restrict__ bucket) {
  if (threadIdx.x == 0) {
    int r = 0, nt = 0;
    for (int e = 0; e < NE; ++e) {
      meta[MI_POFF + e] = r;
      const int cnt = meta[MI_COUNTS + e];
      const int T = (cnt + BM - 1) / BM;
      for (int j = 0; j < T; ++j) {
        meta[MI_TILEE + nt] = e;
        meta[MI_TILER + nt] = r + j * BM;
        meta[MI_TILES0 + nt] = j * BM;
        ++nt;
      }
      r += T * BM;
    }
    meta[MI_POFF + NE] = r;
    meta[MI_NTILES] = nt;
  }
  __syncthreads();
  for (int e = 0; e < NE; ++e) {
    const int cnt = meta[MI_COUNTS + e];
    if (cnt == 0) continue;
    const int padTo = ((cnt + BM - 1) / BM) * BM;
    const int last = bucket[e * NT + cnt - 1];
    for (int i = cnt + threadIdx.x; i < padTo; i += blockDim.x)
      bucket[e * NT + i] = last;
  }
}

// ---------------------------------------------------------------------------
// GEMM body: 128x128 tile, 2-phase gl_lds double buffer, XCD-pinned decode.
// B from the TILED layout: one linear 8 KB tile per K-step.
// MODE 0 -> relu(+b1) bf16 h; MODE 1 -> fp32 partials P[kq].
// ---------------------------------------------------------------------------
template <int MODE>
static __device__ __forceinline__ void gemm_body(
    char* smem, int b, const __hip_bfloat16* __restrict__ A,
    const __hip_bfloat16* __restrict__ B, const float* __restrict__ biasAll,
    const int* __restrict__ meta, const int* __restrict__ bucket,
    void* __restrict__ Out) {
  auto As = reinterpret_cast<__hip_bfloat16(*)[BM][BK]>(smem);
  auto Bs = reinterpret_cast<__hip_bfloat16(*)[BN][BK]>(smem + 16384);

  const int xcd = b & 7;
  const int idx = b >> 3;
  int tile, ntile, kq;
  if (MODE == 0) {
    const int grp = idx / MAXT;
    tile = idx - grp * MAXT;
    ntile = xcd * 4 + grp;
    kq = 0;
  } else {
    const int grp = idx / MAXT;
    tile = idx - grp * MAXT;
    const int np = xcd * 2 + grp;
    ntile = np >> 1;
    kq = np & 1;
  }
  if (tile >= meta[MI_NTILES]) return;

  const int e = meta[MI_TILEE + tile];
  const int row0 = meta[MI_TILER + tile];
  const int s0 = meta[MI_TILES0 + tile];
  const int n0 = ntile * BN;
  const int KTM = (MODE == 0) ? 32 : 64;
  const int kbase = (MODE == 0) ? 0 : kq * (DH / KSPL2);  // A-side k offset
  const int NT1 = (MODE == 0) ? (DH / 128) : (DM / 128);  // 32 : 8
  const int KTcnt = (MODE == 0) ? (DM / 32) : (DH / 32);  // 32 : 128
  const int ktb = (MODE == 0) ? 0 : kq * 64;              // B-side tile base

  const int tid = threadIdx.x;
  const int lane = tid & 63;
  const int wid = tid >> 6;
  const int lr = lane >> 2, lc = lane & 3;

  const __hip_bfloat16 *aP0, *aP1;
  if (MODE == 0) {
    aP0 = A + (size_t)bucket[e * NT + s0 + 32 * wid + lr] * DM + lc * 8;
    aP1 = A + (size_t)bucket[e * NT + s0 + 32 * wid + 16 + lr] * DM + lc * 8;
  } else {
    aP0 = A + (size_t)(row0 + 32 * wid + lr) * DH + kbase + lc * 8;
    aP1 = A + (size_t)(row0 + 32 * wid + 16 + lr) * DH + kbase + lc * 8;
  }
  const __hip_bfloat16* bP0 =
      B + (((size_t)e * NT1 + ntile) * KTcnt + ktb) * 4096 + wid * 1024 +
      lane * 8;
  const __hip_bfloat16* bP1 = bP0 + 512;

  const int wm = (wid >> 1) * 64, wn = (wid & 1) * 64;
  const int fr = lane & 15, ks = lane >> 4;

  f32x4 acc[4][4];
#pragma unroll
  for (int m = 0; m < 4; ++m)
#pragma unroll
    for (int n = 0; n < 4; ++n) acc[m][n] = (f32x4){0.f, 0.f, 0.f, 0.f};

#define STAGE(bf, kt)                                              \
  do {                                                             \
    gload16(aP0 + (size_t)(kt) * BK, &As[bf][32 * wid][0]);        \
    gload16(aP1 + (size_t)(kt) * BK, &As[bf][32 * wid + 16][0]);   \
    gload16(bP0 + (size_t)(kt) * 4096, &Bs[bf][32 * wid][0]);      \
    gload16(bP1 + (size_t)(kt) * 4096, &Bs[bf][32 * wid + 16][0]); \
  } while (0)

  STAGE(0, 0);
  __syncthreads();

  for (int kt = 0; kt < KTM; ++kt) {
    const int buf = kt & 1;
    if (kt + 1 < KTM) STAGE(buf ^ 1, kt + 1);  // loads fly under the MFMAs
    bf16x8 afr[4], bfr[4];
#pragma unroll
    for (int m = 0; m < 4; ++m)
      afr[m] = *(const bf16x8*)&As[buf][wm + m * 16 + fr][ks * 8];
#pragma unroll
    for (int n = 0; n < 4; ++n)
      bfr[n] = *(const bf16x8*)&Bs[buf][wn + n * 16 + fr][ks * 8];
#pragma unroll
    for (int m = 0; m < 4; ++m)
#pragma unroll
      for (int n = 0; n < 4; ++n)
        acc[m][n] = __builtin_amdgcn_mfma_f32_16x16x32_bf16(afr[m], bfr[n],
                                                            acc[m][n], 0, 0, 0);
    __syncthreads();
  }
#undef STAGE

  if (MODE == 0) {
    const float* bias = biasAll + (size_t)e * DH;
    __hip_bfloat16* Hout = (__hip_bfloat16*)Out;
#pragma unroll
    for (int m = 0; m < 4; ++m)
#pragma unroll
      for (int r = 0; r < 4; ++r) {
        const int row = wm + m * 16 + ks * 4 + r;
        __hip_bfloat16* orow = Hout + (size_t)(row0 + row) * DH;
#pragma unroll
        for (int n = 0; n < 4; ++n) {
          const int col = n0 + wn + n * 16 + fr;
          float v = acc[m][n][r] + bias[col];
          orow[col] = __float2bfloat16(v > 0.f ? v : 0.f);
        }
      }
  } else {
    float* Pout = (float*)Out + (size_t)kq * MAXROWS * DM;
#pragma unroll
    for (int m = 0; m < 4; ++m)
#pragma unroll
      for (int r = 0; r < 4; ++r) {
        const int row = wm + m * 16 + ks * 4 + r;
        float* orow = Pout + (size_t)(row0 + row) * DM;
#pragma unroll
        for (int n = 0; n < 4; ++n) {
          const int col = n0 + wn + n * 16 + fr;
          orow[col] = acc[m][n][r];
        }
      }
  }
}

// ---------------------------------------------------------------------------
// Kernel: gemm1 (blocks 0..G1B-1) + convert w2 -> tiled (blocks G1B..+8191).
// gemm1 consumes w1t/bucket; cw2 only reads w2 -> independent, overlapped.
// ---------------------------------------------------------------------------
__global__ __launch_bounds__(256, 2) void gemm1_cw2_kernel(
    const __hip_bfloat16* __restrict__ xb, const __hip_bfloat16* __restrict__ w1t,
    const float* __restrict__ b1, const int* __restrict__ meta,
    const int* __restrict__ bucket, __hip_bfloat16* __restrict__ h,
    const float* __restrict__ w2, __hip_bfloat16* __restrict__ w2t) {
  __shared__ __align__(16) char smem[32768];
  const int bid = blockIdx.x;
  if (bid < G1B) {
    gemm_body<0>(smem, bid, xb, w1t, b1, meta, bucket, (void*)h);
    return;
  }
  const int id = bid - G1B;
  const int e = id & 7;
  const int rem = id >> 3;        // 0..1023
  const int ktg = rem & 63;       // K=4096 -> 64 groups of 64
  const int m = rem >> 6;         // 0..15 (N=1024 / 64)
  convert_v4(w2 + (size_t)e * DH * DM, w2t + (size_t)e * DH * DM, DM,
             DH / 32, ktg * 64, m * 64, smem);
}

// ---------------------------------------------------------------------------
// Kernel: gemm2 (split-K=2).
// ---------------------------------------------------------------------------
__global__ __launch_bounds__(256, 2) void gemm2_kernel(
    const __hip_bfloat16* __restrict__ h, const __hip_bfloat16* __restrict__ w2t,
    const int* __restrict__ meta, const int* __restrict__ bucket,
    float* __restrict__ P) {
  __shared__ __align__(16) char smem[32768];
  gemm_body<1>(smem, blockIdx.x, h, w2t, nullptr, meta, bucket, (void*)P);
}

// ---------------------------------------------------------------------------
// Reduce split-K partials, add b2, scatter padded-row -> token.
// ---------------------------------------------------------------------------
__global__ __launch_bounds__(256) void reduce_out_kernel(
    const float* __restrict__ P, const float* __restrict__ b2,
    const int* __restrict__ meta, const int* __restrict__ bucket,
    float* __restrict__ out) {
  const int gs = blockIdx.x;
  if (gs >= meta[MI_POFF + NE]) return;
  int e = 0;
#pragma unroll
  for (int i = 1; i < NE; ++i) e = (gs >= meta[MI_POFF + i]) ? i : e;
  const int i = gs - meta[MI_POFF + e];
  if (i >= meta[MI_COUNTS + e]) return;  // pad row
  const int tok = bucket[e * NT + i];
  const int c = threadIdx.x * 4;
  float4 v = *(const float4*)(P + (size_t)gs * DM + c);
#pragma unroll
  for (int q = 1; q < KSPL2; ++q) {
    float4 p = *(const float4*)(P + ((size_t)q * MAXROWS + gs) * DM + c);
    v.x += p.x; v.y += p.y; v.z += p.z; v.w += p.w;
  }
  float4 b = *(const float4*)(b2 + (size_t)e * DM + c);
  v.x += b.x; v.y += b.y; v.z += b.z; v.w += b.w;
  *(float4*)(out + (size_t)tok * DM + c) = v;
}

// ---------------------------------------------------------------------------
// Fallback path (small ws): round-1 proven kernels (raw fp32 weights).
// ---------------------------------------------------------------------------
template <bool RELU_BF16>
__global__ __launch_bounds__(256, 2) void moe_gemm_fallback(
    const __hip_bfloat16* __restrict__ Aall, int lda,
    const float* __restrict__ Ball, int K, int N,
    const float* __restrict__ biasAll, const int* __restrict__ counts,
    const int* __restrict__ bucket, void* __restrict__ Out, int ldo) {
  const int e = blockIdx.z;
  const int cnt = counts[e];
  const int m0 = blockIdx.y * BM;
  if (m0 >= cnt) return;
  const int n0 = blockIdx.x * BN;

  const float* Bp = Ball + (size_t)e * K * N;
  const float* bias = biasAll + (size_t)e * N;
  const int* buck = bucket + e * NT;

  __shared__ __align__(16) __hip_bfloat16 As[2][BM][BKP];
  __shared__ __align__(16) __hip_bfloat16 Bs[2][BN][BKP];

  const int tid = threadIdx.x;
  const int lane = tid & 63;
  const int wid = tid >> 6;
  const int wm = (wid >> 1) * 64;
  const int wn = (wid & 1) * 64;
  const int fr = lane & 15;
  const int ks = lane >> 4;

  const int ar = tid >> 1;
  const int ah = tid & 1;
  const int atok = buck[min(m0 + ar, cnt - 1)];
  const __hip_bfloat16* aptr = Aall + (size_t)atok * lda + ah * 16;

  const int bc = tid & 31;
  const int bk0 = (tid >> 5) * 4;

  f32x4 acc[4][4];
#pragma unroll
  for (int m = 0; m < 4; ++m)
#pragma unroll
    for (int n = 0; n < 4; ++n) acc[m][n] = (f32x4){0.f, 0.f, 0.f, 0.f};

  const int KTf = K / BK;
  uint4 ra0, ra1;
  float rb[4][4];

  {
    const uint4* p = (const uint4*)(aptr);
    ra0 = p[0]; ra1 = p[1];
    const float* bbase = Bp + (size_t)bk0 * N + n0 + bc;
#pragma unroll
    for (int i = 0; i < 4; ++i)
#pragma unroll
      for (int j = 0; j < 4; ++j) rb[i][j] = bbase[(size_t)i * N + 32 * j];
  }
  {
    *(uint4*)&As[0][ar][ah * 16] = ra0;
    *(uint4*)&As[0][ar][ah * 16 + 8] = ra1;
#pragma unroll
    for (int j = 0; j < 4; ++j) {
      ushort4 w;
      w.x = f2bf(rb[0][j]); w.y = f2bf(rb[1][j]);
      w.z = f2bf(rb[2][j]); w.w = f2bf(rb[3][j]);
      *(ushort4*)&Bs[0][bc + 32 * j][bk0] = w;
    }
  }
  __syncthreads();

  for (int kt = 0; kt < KTf; ++kt) {
    const int buf = kt & 1;
    if (kt + 1 < KTf) {
      const uint4* p = (const uint4*)(aptr + (size_t)(kt + 1) * BK);
      ra0 = p[0]; ra1 = p[1];
      const float* bbase = Bp + (size_t)((kt + 1) * BK + bk0) * N + n0 + bc;
#pragma unroll
      for (int i = 0; i < 4; ++i)
#pragma unroll
        for (int j = 0; j < 4; ++j) rb[i][j] = bbase[(size_t)i * N + 32 * j];
    }

    bf16x8 afr[4], bfr[4];
#pragma unroll
    for (int m = 0; m < 4; ++m)
      afr[m] = *(const bf16x8*)&As[buf][wm + m * 16 + fr][ks * 8];
#pragma unroll
    for (int n = 0; n < 4; ++n)
      bfr[n] = *(const bf16x8*)&Bs[buf][wn + n * 16 + fr][ks * 8];
#pragma unroll
    for (int m = 0; m < 4; ++m)
#pragma unroll
      for (int n = 0; n < 4; ++n)
        acc[m][n] = __builtin_amdgcn_mfma_f32_16x16x32_bf16(afr[m], bfr[n],
                                                            acc[m][n], 0, 0, 0);

    __syncthreads();
    if (kt + 1 < KTf) {
      *(uint4*)&As[buf ^ 1][ar][ah * 16] = ra0;
      *(uint4*)&As[buf ^ 1][ar][ah * 16 + 8] = ra1;
#pragma unroll
      for (int j = 0; j < 4; ++j) {
        ushort4 w;
        w.x = f2bf(rb[0][j]); w.y = f2bf(rb[1][j]);
        w.z = f2bf(rb[2][j]); w.w = f2bf(rb[3][j]);
        *(ushort4*)&Bs[buf ^ 1][bc + 32 * j][bk0] = w;
      }
      __syncthreads();
    }
  }

  float* outF = (float*)Out;
  __hip_bfloat16* outB = (__hip_bfloat16*)Out;
#pragma unroll
  for (int m = 0; m < 4; ++m) {
#pragma unroll
    for (int r = 0; r < 4; ++r) {
      const int row = wm + m * 16 + ks * 4 + r;
      const int slot = m0 + row;
      if (slot < cnt) {
        const int tok = buck[slot];
#pragma unroll
        for (int n = 0; n < 4; ++n) {
          const int col = n0 + wn + n * 16 + fr;
          float v = acc[m][n][r] + bias[col];
          if (RELU_BF16) {
            v = v > 0.f ? v : 0.f;
            outB[(size_t)tok * ldo + col] = __float2bfloat16(v);
          } else {
            outF[(size_t)tok * ldo + col] = v;
          }
        }
      }
    }
  }
}

extern "C" void kernel_launch(void* const* d_in, const int* in_sizes, int n_in,
                              void* d_out, int out_size, void* d_ws,
                              size_t ws_size, hipStream_t stream) {
  const float* x = (const float*)d_in[0];
  const float* gw = (const float*)d_in[1];
  const float* gb = (const float*)d_in[2];
  const float* w1 = (const float*)d_in[3];
  const float* b1 = (const float*)d_in[4];
  const float* w2 = (const float*)d_in[5];
  const float* b2 = (const float*)d_in[6];
  (void)in_sizes; (void)n_in; (void)out_size;

  char* ws = (char*)d_ws;
  int* meta = (int*)ws;
  int* counts = meta + MI_COUNTS;
  int* bucket = (int*)(ws + O_BUCKET);
  __hip_bfloat16* xb = (__hip_bfloat16*)(ws + O_XB);
  __hip_bfloat16* h = (__hip_bfloat16*)(ws + O_H);

  hipMemsetAsync(ws, 0, 1024, stream);

  if (ws_size >= WS_NEED) {
    __hip_bfloat16* w1t = (__hip_bfloat16*)(ws + O_W1T);
    __hip_bfloat16* w2t = (__hip_bfloat16*)(ws + O_W2T);
    float* P = (float*)(ws + O_P);

    gate_route_kernel<<<NT / 4, 256, 0, stream>>>(x, gw, gb, counts, bucket,
                                                  xb);
    cw1_kernel<<<8192, 256, 0, stream>>>(w1, w1t);
    prefix_kernel<<<1, 256, 0, stream>>>(meta, bucket);
    gemm1_cw2_kernel<<<G1B + 8192, 256, 0, stream>>>(
        xb, w1t, b1, meta, bucket, h, w2, w2t);
    gemm2_kernel<<<8 * 2 * MAXT, 256, 0, stream>>>(h, w2t, meta, bucket, P);
    reduce_out_kernel<<<MAXROWS, 256, 0, stream>>>(P, b2, meta, bucket,
                                                   (float*)d_out);
  } else {
    gate_route_kernel<<<NT / 4, 256, 0, stream>>>(x, gw, gb, counts, bucket,
                                                  xb);
    dim3 g1(DH / BN, NT / BM, NE);
    moe_gemm_fallback<true><<<g1, 256, 0, stream>>>(
        xb, DM, w1, DM, DH, b1, counts, bucket, (void*)h, DH);
    dim3 g2(DM / BN, NT / BM, NE);
    moe_gemm_fallback<false><<<g2, 256, 0, stream>>>(
        h, DH, w2, DH, DM, b2, counts, bucket, d_out, DM);
  }
}

// Round 13
// 264.058 us; speedup vs baseline: 1.0499x; 1.0499x over previous
//
#include <hip/hip_runtime.h>
#include <hip/hip_bf16.h>

#define NT 4096   // tokens
#define DM 1024   // d_model
#define DH 4096   // d_hidden
#define NE 8      // experts

#define BM 128
#define BN 128
#define BK 32
#define MAXT 40      // max padded M-tiles
#define MAXROWS 5120 // 40*128
#define KSPL2 2      // split-K for GEMM2 (K-window 2048)
#define BKP 40       // fallback LDS pad
#define G1B (8 * 4 * MAXT)  // gemm1 block count (1280)

typedef short bf16x8 __attribute__((ext_vector_type(8)));
typedef float f32x4 __attribute__((ext_vector_type(4)));
typedef float f4 __attribute__((ext_vector_type(4)));

// meta ints at ws base
#define MI_COUNTS 0
#define MI_POFF   16
#define MI_NTILES 32
#define MI_TILEE  48
#define MI_TILER  112
#define MI_TILES0 176

#define O_BUCKET 1024ull
#define O_XB  (O_BUCKET + (size_t)NE * NT * 4)
#define O_H   (O_XB + (size_t)NT * DM * 2)                     // +8 MB
#define O_W1T (O_H + (size_t)MAXROWS * DH * 2)                 // +40 MB
#define O_W2T (O_W1T + (size_t)NE * DM * DH * 2)               // +64 MB
#define WS_NEED (O_W2T + (size_t)NE * DH * DM * 2)             // ~176 MiB
#define O_P   O_W1T   // split-K partials alias dead w1t

static __device__ __forceinline__ unsigned short f2bf(float f) {
  union { __hip_bfloat16 h; unsigned short u; } cv;
  cv.h = __float2bfloat16(f);
  return cv.u;
}

static __device__ __forceinline__ void gload16(const void* g, void* l) {
  __builtin_amdgcn_global_load_lds(
      (const __attribute__((address_space(1))) void*)g,
      (__attribute__((address_space(3))) void*)l, 16, 0, 0);
}

// ---------------------------------------------------------------------------
// Tiled weight layout: bf16 tiles [128 n'][32 k'] (8 KB, row=64B), ordered
// [e][ntile][kt] with kt fastest. Tile (e,nt,kt) elem (n',k') =
// W[e][kt*32+k'][nt*128+n'].
//
// convert_v4: one block converts a 64k x 64n region of fp32 [K][N] into the
// corresponding halves of two k-tiles. IMPORTANT (r6 vs r9-r12 lesson): the
// GRID decode must sweep n fastest so temporally-adjacent blocks read
// contiguous k-rows of the fp32 source (DRAM open-page streams); k-fastest
// decodes cut convert throughput ~2x.
// ---------------------------------------------------------------------------
static __device__ __forceinline__ void convert_v4(
    const float* __restrict__ S, __hip_bfloat16* __restrict__ D, int N,
    int KTcnt, int kglob0, int nglob0, char* smem) {
  auto Ls = reinterpret_cast<__hip_bfloat16(*)[72]>(smem);  // [64][72]
  const int tid = threadIdx.x;
  const int c4 = tid & 15, rk = tid >> 4;
  const float* src = S + (size_t)(kglob0 + rk * 4) * N + nglob0 + c4 * 4;
  f4 v[4];
#pragma unroll
  for (int j = 0; j < 4; ++j) v[j] = *(const f4*)(src + (size_t)j * N);
#pragma unroll
  for (int i = 0; i < 4; ++i) {
    ushort4 w;
    w.x = f2bf(v[0][i]); w.y = f2bf(v[1][i]);
    w.z = f2bf(v[2][i]); w.w = f2bf(v[3][i]);
    *(ushort4*)&Ls[c4 * 4 + i][rk * 4] = w;  // Ls[nl][kl..kl+3]
  }
  __syncthreads();
  const int r = tid >> 2, q = tid & 3;
  const int nt = nglob0 >> 7;
  const int npr = (nglob0 & 64) + r;  // row within the 128-row tile
#pragma unroll
  for (int u = 0; u < 2; ++u) {
    const int g = q * 2 + u;                  // k-granule 0..7 (8 k each)
    const int kt = (kglob0 >> 5) + (g >> 2);  // which k-tile
    uint4 w = *(const uint4*)&Ls[r][g * 8];
    *(uint4*)(D + ((size_t)nt * KTcnt + kt) * 4096 + npr * 32 + (g & 3) * 8) =
        w;
  }
}

// ---------------------------------------------------------------------------
// Gate wave body: 8 logits (double accum -> first-max argmax), bucket
// scatter, x -> bf16.
// ---------------------------------------------------------------------------
static __device__ __forceinline__ void gate_body(
    const float* __restrict__ x, const float* __restrict__ gw,
    const float* __restrict__ gb, int* __restrict__ counts,
    int* __restrict__ bucket, __hip_bfloat16* __restrict__ xb, int bid) {
  const int tid = threadIdx.x;
  const int wid = tid >> 6;
  const int lane = tid & 63;
  const int t = bid * 4 + wid;

  const f4* xrow = (const f4*)(x + (size_t)t * DM);
  ushort4* xbrow = (ushort4*)(xb + (size_t)t * DM);

  double part[NE];
#pragma unroll
  for (int e = 0; e < NE; ++e) part[e] = 0.0;

#pragma unroll
  for (int q = 0; q < 4; ++q) {
    f4 v = xrow[q * 64 + lane];
    ushort4 s;
    s.x = f2bf(v[0]); s.y = f2bf(v[1]); s.z = f2bf(v[2]); s.w = f2bf(v[3]);
    xbrow[q * 64 + lane] = s;
#pragma unroll
    for (int e = 0; e < NE; ++e) {
      f4 w = ((const f4*)(gw + (size_t)e * DM))[q * 64 + lane];
      part[e] += (double)v[0] * w[0] + (double)v[1] * w[1] +
                 (double)v[2] * w[2] + (double)v[3] * w[3];
    }
  }
#pragma unroll
  for (int off = 32; off; off >>= 1) {
#pragma unroll
    for (int e = 0; e < NE; ++e) part[e] += __shfl_down(part[e], off);
  }
  if (lane == 0) {
    double best = part[0] + (double)gb[0];
    int bi = 0;
#pragma unroll
    for (int e = 1; e < NE; ++e) {
      double le = part[e] + (double)gb[e];
      if (le > best) { best = le; bi = e; }
    }
    int pos = atomicAdd(&counts[bi], 1);
    bucket[bi * NT + pos] = t;
  }
}

__global__ __launch_bounds__(256) void gate_route_kernel(
    const float* __restrict__ x, const float* __restrict__ gw,
    const float* __restrict__ gb, int* __restrict__ counts,
    int* __restrict__ bucket, __hip_bfloat16* __restrict__ xb) {
  gate_body(x, gw, gb, counts, bucket, xb, blockIdx.x);
}

// ---------------------------------------------------------------------------
// cw1: standalone convert of w1 -> tiled. 8192 blocks, r6's proven decode:
// e = id>>10 (expert slowest), n0 FASTEST so consecutive blocks tile whole
// contiguous source k-rows (256B x 16 blocks = 16KB row).
// ---------------------------------------------------------------------------
__global__ __launch_bounds__(256) void cw1_kernel(
    const float* __restrict__ w1, __hip_bfloat16* __restrict__ w1t) {
  __shared__ __align__(16) char smem[9216];
  const int id = blockIdx.x;
  const int e = id >> 10;
  const int rem = id & 1023;           // 16 kg x 64 ng
  const int kglob0 = (rem >> 6) * 64;  // k slowest
  const int nglob0 = (rem & 63) * 64;  // n fastest
  convert_v4(w1 + (size_t)e * DM * DH, w1t + (size_t)e * DM * DH, DH,
             DM / 32, kglob0, nglob0, smem);
}

// ---------------------------------------------------------------------------
// Prefix + padded tile table + bucket padding.
// ---------------------------------------------------------------------------
__global__ void prefix_kernel(int* __restrict__ meta, int* __restrict__ bucket) {
  if (threadIdx.x == 0) {
    int r = 0, nt = 0;
    for (int e = 0; e < NE; ++e) {
      meta[MI_POFF + e] = r;
      const int cnt = meta[MI_COUNTS + e];
      const int T = (cnt + BM - 1) / BM;
      for (int j = 0; j < T; ++j) {
        meta[MI_TILEE + nt] = e;
        meta[MI_TILER + nt] = r + j * BM;
        meta[MI_TILES0 + nt] = j * BM;
        ++nt;
      }
      r += T * BM;
    }
    meta[MI_POFF + NE] = r;
    meta[MI_NTILES] = nt;
  }
  __syncthreads();
  for (int e = 0; e < NE; ++e) {
    const int cnt = meta[MI_COUNTS + e];
    if (cnt == 0) continue;
    const int padTo = ((cnt + BM - 1) / BM) * BM;
    const int last = bucket[e * NT + cnt - 1];
    for (int i = cnt + threadIdx.x; i < padTo; i += blockDim.x)
      bucket[e * NT + i] = last;
  }
}

// ---------------------------------------------------------------------------
// GEMM body: 128x128 tile, 2-phase gl_lds double buffer, XCD-pinned decode.
// B from the TILED layout: one linear 8 KB tile per K-step.
// MODE 0 -> relu(+b1) bf16 h; MODE 1 -> fp32 partials P[kq].
// ---------------------------------------------------------------------------
template <int MODE>
static __device__ __forceinline__ void gemm_body(
    char* smem, int b, const __hip_bfloat16* __restrict__ A,
    const __hip_bfloat16* __restrict__ B, const float* __restrict__ biasAll,
    const int* __restrict__ meta, const int* __restrict__ bucket,
    void* __restrict__ Out) {
  auto As = reinterpret_cast<__hip_bfloat16(*)[BM][BK]>(smem);
  auto Bs = reinterpret_cast<__hip_bfloat16(*)[BN][BK]>(smem + 16384);

  const int xcd = b & 7;
  const int idx = b >> 3;
  int tile, ntile, kq;
  if (MODE == 0) {
    const int grp = idx / MAXT;
    tile = idx - grp * MAXT;
    ntile = xcd * 4 + grp;
    kq = 0;
  } else {
    const int grp = idx / MAXT;
    tile = idx - grp * MAXT;
    const int np = xcd * 2 + grp;
    ntile = np >> 1;
    kq = np & 1;
  }
  if (tile >= meta[MI_NTILES]) return;

  const int e = meta[MI_TILEE + tile];
  const int row0 = meta[MI_TILER + tile];
  const int s0 = meta[MI_TILES0 + tile];
  const int n0 = ntile * BN;
  const int KTM = (MODE == 0) ? 32 : 64;
  const int kbase = (MODE == 0) ? 0 : kq * (DH / KSPL2);  // A-side k offset
  const int NT1 = (MODE == 0) ? (DH / 128) : (DM / 128);  // 32 : 8
  const int KTcnt = (MODE == 0) ? (DM / 32) : (DH / 32);  // 32 : 128
  const int ktb = (MODE == 0) ? 0 : kq * 64;              // B-side tile base

  const int tid = threadIdx.x;
  const int lane = tid & 63;
  const int wid = tid >> 6;
  const int lr = lane >> 2, lc = lane & 3;

  const __hip_bfloat16 *aP0, *aP1;
  if (MODE == 0) {
    aP0 = A + (size_t)bucket[e * NT + s0 + 32 * wid + lr] * DM + lc * 8;
    aP1 = A + (size_t)bucket[e * NT + s0 + 32 * wid + 16 + lr] * DM + lc * 8;
  } else {
    aP0 = A + (size_t)(row0 + 32 * wid + lr) * DH + kbase + lc * 8;
    aP1 = A + (size_t)(row0 + 32 * wid + 16 + lr) * DH + kbase + lc * 8;
  }
  const __hip_bfloat16* bP0 =
      B + (((size_t)e * NT1 + ntile) * KTcnt + ktb) * 4096 + wid * 1024 +
      lane * 8;
  const __hip_bfloat16* bP1 = bP0 + 512;

  const int wm = (wid >> 1) * 64, wn = (wid & 1) * 64;
  const int fr = lane & 15, ks = lane >> 4;

  f32x4 acc[4][4];
#pragma unroll
  for (int m = 0; m < 4; ++m)
#pragma unroll
    for (int n = 0; n < 4; ++n) acc[m][n] = (f32x4){0.f, 0.f, 0.f, 0.f};

#define STAGE(bf, kt)                                              \
  do {                                                             \
    gload16(aP0 + (size_t)(kt) * BK, &As[bf][32 * wid][0]);        \
    gload16(aP1 + (size_t)(kt) * BK, &As[bf][32 * wid + 16][0]);   \
    gload16(bP0 + (size_t)(kt) * 4096, &Bs[bf][32 * wid][0]);      \
    gload16(bP1 + (size_t)(kt) * 4096, &Bs[bf][32 * wid + 16][0]); \
  } while (0)

  STAGE(0, 0);
  __syncthreads();

  for (int kt = 0; kt < KTM; ++kt) {
    const int buf = kt & 1;
    if (kt + 1 < KTM) STAGE(buf ^ 1, kt + 1);  // loads fly under the MFMAs
    bf16x8 afr[4], bfr[4];
#pragma unroll
    for (int m = 0; m < 4; ++m)
      afr[m] = *(const bf16x8*)&As[buf][wm + m * 16 + fr][ks * 8];
#pragma unroll
    for (int n = 0; n < 4; ++n)
      bfr[n] = *(const bf16x8*)&Bs[buf][wn + n * 16 + fr][ks * 8];
#pragma unroll
    for (int m = 0; m < 4; ++m)
#pragma unroll
      for (int n = 0; n < 4; ++n)
        acc[m][n] = __builtin_amdgcn_mfma_f32_16x16x32_bf16(afr[m], bfr[n],
                                                            acc[m][n], 0, 0, 0);
    __syncthreads();
  }
#undef STAGE

  if (MODE == 0) {
    const float* bias = biasAll + (size_t)e * DH;
    __hip_bfloat16* Hout = (__hip_bfloat16*)Out;
#pragma unroll
    for (int m = 0; m < 4; ++m)
#pragma unroll
      for (int r = 0; r < 4; ++r) {
        const int row = wm + m * 16 + ks * 4 + r;
        __hip_bfloat16* orow = Hout + (size_t)(row0 + row) * DH;
#pragma unroll
        for (int n = 0; n < 4; ++n) {
          const int col = n0 + wn + n * 16 + fr;
          float v = acc[m][n][r] + bias[col];
          orow[col] = __float2bfloat16(v > 0.f ? v : 0.f);
        }
      }
  } else {
    float* Pout = (float*)Out + (size_t)kq * MAXROWS * DM;
#pragma unroll
    for (int m = 0; m < 4; ++m)
#pragma unroll
      for (int r = 0; r < 4; ++r) {
        const int row = wm + m * 16 + ks * 4 + r;
        float* orow = Pout + (size_t)(row0 + row) * DM;
#pragma unroll
        for (int n = 0; n < 4; ++n) {
          const int col = n0 + wn + n * 16 + fr;
          orow[col] = acc[m][n][r];
        }
      }
  }
}

// ---------------------------------------------------------------------------
// Kernel: gemm1 (blocks 0..G1B-1) + convert w2 -> tiled (blocks G1B..+8191).
// cw2 decode n-fastest (same page-locality rule); gemm1 and cw2 independent.
// ---------------------------------------------------------------------------
__global__ __launch_bounds__(256, 2) void gemm1_cw2_kernel(
    const __hip_bfloat16* __restrict__ xb, const __hip_bfloat16* __restrict__ w1t,
    const float* __restrict__ b1, const int* __restrict__ meta,
    const int* __restrict__ bucket, __hip_bfloat16* __restrict__ h,
    const float* __restrict__ w2, __hip_bfloat16* __restrict__ w2t) {
  __shared__ __align__(16) char smem[32768];
  const int bid = blockIdx.x;
  if (bid < G1B) {
    gemm_body<0>(smem, bid, xb, w1t, b1, meta, bucket, (void*)h);
    return;
  }
  const int id = bid - G1B;
  const int e = id >> 10;
  const int rem = id & 1023;           // 64 kg x 16 ng
  const int kglob0 = (rem >> 4) * 64;  // k slowest
  const int nglob0 = (rem & 15) * 64;  // n fastest
  convert_v4(w2 + (size_t)e * DH * DM, w2t + (size_t)e * DH * DM, DM,
             DH / 32, kglob0, nglob0, smem);
}

// ---------------------------------------------------------------------------
// Kernel: gemm2 (split-K=2).
// ---------------------------------------------------------------------------
__global__ __launch_bounds__(256, 2) void gemm2_kernel(
    const __hip_bfloat16* __restrict__ h, const __hip_bfloat16* __restrict__ w2t,
    const int* __restrict__ meta, const int* __restrict__ bucket,
    float* __restrict__ P) {
  __shared__ __align__(16) char smem[32768];
  gemm_body<1>(smem, blockIdx.x, h, w2t, nullptr, meta, bucket, (void*)P);
}

// ---------------------------------------------------------------------------
// Reduce split-K partials, add b2, scatter padded-row -> token.
// ---------------------------------------------------------------------------
__global__ __launch_bounds__(256) void reduce_out_kernel(
    const float* __restrict__ P, const float* __restrict__ b2,
    const int* __restrict__ meta, const int* __restrict__ bucket,
    float* __restrict__ out) {
  const int gs = blockIdx.x;
  if (gs >= meta[MI_POFF + NE]) return;
  int e = 0;
#pragma unroll
  for (int i = 1; i < NE; ++i) e = (gs >= meta[MI_POFF + i]) ? i : e;
  const int i = gs - meta[MI_POFF + e];
  if (i >= meta[MI_COUNTS + e]) return;  // pad row
  const int tok = bucket[e * NT + i];
  const int c = threadIdx.x * 4;
  float4 v = *(const float4*)(P + (size_t)gs * DM + c);
#pragma unroll
  for (int q = 1; q < KSPL2; ++q) {
    float4 p = *(const float4*)(P + ((size_t)q * MAXROWS + gs) * DM + c);
    v.x += p.x; v.y += p.y; v.z += p.z; v.w += p.w;
  }
  float4 b = *(const float4*)(b2 + (size_t)e * DM + c);
  v.x += b.x; v.y += b.y; v.z += b.z; v.w += b.w;
  *(float4*)(out + (size_t)tok * DM + c) = v;
}

// ---------------------------------------------------------------------------
// Fallback path (small ws): round-1 proven kernels (raw fp32 weights).
// ---------------------------------------------------------------------------
template <bool RELU_BF16>
__global__ __launch_bounds__(256, 2) void moe_gemm_fallback(
    const __hip_bfloat16* __restrict__ Aall, int lda,
    const float* __restrict__ Ball, int K, int N,
    const float* __restrict__ biasAll, const int* __restrict__ counts,
    const int* __restrict__ bucket, void* __restrict__ Out, int ldo) {
  const int e = blockIdx.z;
  const int cnt = counts[e];
  const int m0 = blockIdx.y * BM;
  if (m0 >= cnt) return;
  const int n0 = blockIdx.x * BN;

  const float* Bp = Ball + (size_t)e * K * N;
  const float* bias = biasAll + (size_t)e * N;
  const int* buck = bucket + e * NT;

  __shared__ __align__(16) __hip_bfloat16 As[2][BM][BKP];
  __shared__ __align__(16) __hip_bfloat16 Bs[2][BN][BKP];

  const int tid = threadIdx.x;
  const int lane = tid & 63;
  const int wid = tid >> 6;
  const int wm = (wid >> 1) * 64;
  const int wn = (wid & 1) * 64;
  const int fr = lane & 15;
  const int ks = lane >> 4;

  const int ar = tid >> 1;
  const int ah = tid & 1;
  const int atok = buck[min(m0 + ar, cnt - 1)];
  const __hip_bfloat16* aptr = Aall + (size_t)atok * lda + ah * 16;

  const int bc = tid & 31;
  const int bk0 = (tid >> 5) * 4;

  f32x4 acc[4][4];
#pragma unroll
  for (int m = 0; m < 4; ++m)
#pragma unroll
    for (int n = 0; n < 4; ++n) acc[m][n] = (f32x4){0.f, 0.f, 0.f, 0.f};

  const int KTf = K / BK;
  uint4 ra0, ra1;
  float rb[4][4];

  {
    const uint4* p = (const uint4*)(aptr);
    ra0 = p[0]; ra1 = p[1];
    const float* bbase = Bp + (size_t)bk0 * N + n0 + bc;
#pragma unroll
    for (int i = 0; i < 4; ++i)
#pragma unroll
      for (int j = 0; j < 4; ++j) rb[i][j] = bbase[(size_t)i * N + 32 * j];
  }
  {
    *(uint4*)&As[0][ar][ah * 16] = ra0;
    *(uint4*)&As[0][ar][ah * 16 + 8] = ra1;
#pragma unroll
    for (int j = 0; j < 4; ++j) {
      ushort4 w;
      w.x = f2bf(rb[0][j]); w.y = f2bf(rb[1][j]);
      w.z = f2bf(rb[2][j]); w.w = f2bf(rb[3][j]);
      *(ushort4*)&Bs[0][bc + 32 * j][bk0] = w;
    }
  }
  __syncthreads();

  for (int kt = 0; kt < KTf; ++kt) {
    const int buf = kt & 1;
    if (kt + 1 < KTf) {
      const uint4* p = (const uint4*)(aptr + (size_t)(kt + 1) * BK);
      ra0 = p[0]; ra1 = p[1];
      const float* bbase = Bp + (size_t)((kt + 1) * BK + bk0) * N + n0 + bc;
#pragma unroll
      for (int i = 0; i < 4; ++i)
#pragma unroll
        for (int j = 0; j < 4; ++j) rb[i][j] = bbase[(size_t)i * N + 32 * j];
    }

    bf16x8 afr[4], bfr[4];
#pragma unroll
    for (int m = 0; m < 4; ++m)
      afr[m] = *(const bf16x8*)&As[buf][wm + m * 16 + fr][ks * 8];
#pragma unroll
    for (int n = 0; n < 4; ++n)
      bfr[n] = *(const bf16x8*)&Bs[buf][wn + n * 16 + fr][ks * 8];
#pragma unroll
    for (int m = 0; m < 4; ++m)
#pragma unroll
      for (int n = 0; n < 4; ++n)
        acc[m][n] = __builtin_amdgcn_mfma_f32_16x16x32_bf16(afr[m], bfr[n],
                                                            acc[m][n], 0, 0, 0);

    __syncthreads();
    if (kt + 1 < KTf) {
      *(uint4*)&As[buf ^ 1][ar][ah * 16] = ra0;
      *(uint4*)&As[buf ^ 1][ar][ah * 16 + 8] = ra1;
#pragma unroll
      for (int j = 0; j < 4; ++j) {
        ushort4 w;
        w.x = f2bf(rb[0][j]); w.y = f2bf(rb[1][j]);
        w.z = f2bf(rb[2][j]); w.w = f2bf(rb[3][j]);
        *(uint2*)&Bs[buf ^ 1][bc + 32 * j][bk0] = *(uint2*)&w;
      }
      __syncthreads();
    }
  }

  float* outF = (float*)Out;
  __hip_bfloat16* outB = (__hip_bfloat16*)Out;
#pragma unroll
  for (int m = 0; m < 4; ++m) {
#pragma unroll
    for (int r = 0; r < 4; ++r) {
      const int row = wm + m * 16 + ks * 4 + r;
      const int slot = m0 + row;
      if (slot < cnt) {
        const int tok = buck[slot];
#pragma unroll
        for (int n = 0; n < 4; ++n) {
          const int col = n0 + wn + n * 16 + fr;
          float v = acc[m][n][r] + bias[col];
          if (RELU_BF16) {
            v = v > 0.f ? v : 0.f;
            outB[(size_t)tok * ldo + col] = __float2bfloat16(v);
          } else {
            outF[(size_t)tok * ldo + col] = v;
          }
        }
      }
    }
  }
}

extern "C" void kernel_launch(void* const* d_in, const int* in_sizes, int n_in,
                              void* d_out, int out_size, void* d_ws,
                              size_t ws_size, hipStream_t stream) {
  const float* x = (const float*)d_in[0];
  const float* gw = (const float*)d_in[1];
  const float* gb = (const float*)d_in[2];
  const float* w1 = (const float*)d_in[3];
  const float* b1 = (const float*)d_in[4];
  const float* w2 = (const float*)d_in[5];
  const float* b2 = (const float*)d_in[6];
  (void)in_sizes; (void)n_in; (void)out_size;

  char* ws = (char*)d_ws;
  int* meta = (int*)ws;
  int* counts = meta + MI_COUNTS;
  int* bucket = (int*)(ws + O_BUCKET);
  __hip_bfloat16* xb = (__hip_bfloat16*)(ws + O_XB);
  __hip_bfloat16* h = (__hip_bfloat16*)(ws + O_H);

  hipMemsetAsync(ws, 0, 1024, stream);

  if (ws_size >= WS_NEED) {
    __hip_bfloat16* w1t = (__hip_bfloat16*)(ws + O_W1T);
    __hip_bfloat16* w2t = (__hip_bfloat16*)(ws + O_W2T);
    float* P = (float*)(ws + O_P);

    gate_route_kernel<<<NT / 4, 256, 0, stream>>>(x, gw, gb, counts, bucket,
                                                  xb);
    cw1_kernel<<<8192, 256, 0, stream>>>(w1, w1t);
    prefix_kernel<<<1, 256, 0, stream>>>(meta, bucket);
    gemm1_cw2_kernel<<<G1B + 8192, 256, 0, stream>>>(
        xb, w1t, b1, meta, bucket, h, w2, w2t);
    gemm2_kernel<<<8 * 2 * MAXT, 256, 0, stream>>>(h, w2t, meta, bucket, P);
    reduce_out_kernel<<<MAXROWS, 256, 0, stream>>>(P, b2, meta, bucket,
                                                   (float*)d_out);
  } else {
    gate_route_kernel<<<NT / 4, 256, 0, stream>>>(x, gw, gb, counts, bucket,
                                                  xb);
    dim3 g1(DH / BN, NT / BM, NE);
    moe_gemm_fallback<true><<<g1, 256, 0, stream>>>(
        xb, DM, w1, DM, DH, b1, counts, bucket, (void*)h, DH);
    dim3 g2(DM / BN, NT / BM, NE);
    moe_gemm_fallback<false><<<g2, 256, 0, stream>>>(
        h, DH, w2, DH, DM, b2, counts, bucket, d_out, DM);
  }
}

// Round 14
// 251.406 us; speedup vs baseline: 1.1027x; 1.0503x over previous
//
#include <hip/hip_runtime.h>
#include <hip/hip_bf16.h>

#define NT 4096   // tokens
#define DM 1024   // d_model
#define DH 4096   // d_hidden
#define NE 8      // experts

#define BM 128
#define BN 128
#define BK 32
#define MAXT 40      // max padded M-tiles
#define MAXROWS 5120 // 40*128
#define KSPL2 2      // split-K for GEMM2 (K-window 2048)
#define BKP 40       // padded B LDS k-stride (80 B)
#define G1B (8 * 4 * MAXT)  // gemm1 block count (1280)

typedef short bf16x8 __attribute__((ext_vector_type(8)));
typedef float f32x4 __attribute__((ext_vector_type(4)));
typedef float f4 __attribute__((ext_vector_type(4)));

// meta ints at ws base
#define MI_COUNTS 0
#define MI_POFF   16
#define MI_NTILES 32
#define MI_TILEE  48
#define MI_TILER  112
#define MI_TILES0 176

#define O_BUCKET 1024ull
#define O_XB  (O_BUCKET + (size_t)NE * NT * 4)
#define O_H   (O_XB + (size_t)NT * DM * 2)                     // +8 MB
#define O_W1T (O_H + (size_t)MAXROWS * DH * 2)                 // +40 MB (P alias)
#define O_W2T (O_W1T + (size_t)NE * DM * DH * 2)               // +64 MB
#define WS_NEED (O_W2T + (size_t)NE * DH * DM * 2)             // ~176 MiB
#define O_P   O_W1T   // split-K partials alias unused w1t region

static __device__ __forceinline__ unsigned short f2bf(float f) {
  union { __hip_bfloat16 h; unsigned short u; } cv;
  cv.h = __float2bfloat16(f);
  return cv.u;
}

static __device__ __forceinline__ void gload16(const void* g, void* l) {
  __builtin_amdgcn_global_load_lds(
      (const __attribute__((address_space(1))) void*)g,
      (__attribute__((address_space(3))) void*)l, 16, 0, 0);
}

// ---------------------------------------------------------------------------
// Tiled weight layout (w2t only now): bf16 tiles [128 n'][32 k'] (8 KB),
// ordered [e][ntile][kt], kt fastest. convert_v4: 64k x 64n region -> halves
// of two k-tiles. Grid decode must sweep n fastest (DRAM page streams).
// ---------------------------------------------------------------------------
static __device__ __forceinline__ void convert_v4(
    const float* __restrict__ S, __hip_bfloat16* __restrict__ D, int N,
    int KTcnt, int kglob0, int nglob0, char* smem) {
  auto Ls = reinterpret_cast<__hip_bfloat16(*)[72]>(smem);  // [64][72]
  const int tid = threadIdx.x;
  const int c4 = tid & 15, rk = tid >> 4;
  const float* src = S + (size_t)(kglob0 + rk * 4) * N + nglob0 + c4 * 4;
  f4 v[4];
#pragma unroll
  for (int j = 0; j < 4; ++j) v[j] = *(const f4*)(src + (size_t)j * N);
#pragma unroll
  for (int i = 0; i < 4; ++i) {
    ushort4 w;
    w.x = f2bf(v[0][i]); w.y = f2bf(v[1][i]);
    w.z = f2bf(v[2][i]); w.w = f2bf(v[3][i]);
    *(ushort4*)&Ls[c4 * 4 + i][rk * 4] = w;
  }
  __syncthreads();
  const int r = tid >> 2, q = tid & 3;
  const int nt = nglob0 >> 7;
  const int npr = (nglob0 & 64) + r;
#pragma unroll
  for (int u = 0; u < 2; ++u) {
    const int g = q * 2 + u;
    const int kt = (kglob0 >> 5) + (g >> 2);
    uint4 w = *(const uint4*)&Ls[r][g * 8];
    *(uint4*)(D + ((size_t)nt * KTcnt + kt) * 4096 + npr * 32 + (g & 3) * 8) =
        w;
  }
}

// ---------------------------------------------------------------------------
// Gate wave body.
// ---------------------------------------------------------------------------
static __device__ __forceinline__ void gate_body(
    const float* __restrict__ x, const float* __restrict__ gw,
    const float* __restrict__ gb, int* __restrict__ counts,
    int* __restrict__ bucket, __hip_bfloat16* __restrict__ xb, int bid) {
  const int tid = threadIdx.x;
  const int wid = tid >> 6;
  const int lane = tid & 63;
  const int t = bid * 4 + wid;

  const f4* xrow = (const f4*)(x + (size_t)t * DM);
  ushort4* xbrow = (ushort4*)(xb + (size_t)t * DM);

  double part[NE];
#pragma unroll
  for (int e = 0; e < NE; ++e) part[e] = 0.0;

#pragma unroll
  for (int q = 0; q < 4; ++q) {
    f4 v = xrow[q * 64 + lane];
    ushort4 s;
    s.x = f2bf(v[0]); s.y = f2bf(v[1]); s.z = f2bf(v[2]); s.w = f2bf(v[3]);
    xbrow[q * 64 + lane] = s;
#pragma unroll
    for (int e = 0; e < NE; ++e) {
      f4 w = ((const f4*)(gw + (size_t)e * DM))[q * 64 + lane];
      part[e] += (double)v[0] * w[0] + (double)v[1] * w[1] +
                 (double)v[2] * w[2] + (double)v[3] * w[3];
    }
  }
#pragma unroll
  for (int off = 32; off; off >>= 1) {
#pragma unroll
    for (int e = 0; e < NE; ++e) part[e] += __shfl_down(part[e], off);
  }
  if (lane == 0) {
    double best = part[0] + (double)gb[0];
    int bi = 0;
#pragma unroll
    for (int e = 1; e < NE; ++e) {
      double le = part[e] + (double)gb[e];
      if (le > best) { best = le; bi = e; }
    }
    int pos = atomicAdd(&counts[bi], 1);
    bucket[bi * NT + pos] = t;
  }
}

__global__ __launch_bounds__(256) void gate_route_kernel(
    const float* __restrict__ x, const float* __restrict__ gw,
    const float* __restrict__ gb, int* __restrict__ counts,
    int* __restrict__ bucket, __hip_bfloat16* __restrict__ xb) {
  gate_body(x, gw, gb, counts, bucket, xb, blockIdx.x);
}

// ---------------------------------------------------------------------------
// Prefix + padded tile table + bucket padding.
// ---------------------------------------------------------------------------
__global__ void prefix_kernel(int* __restrict__ meta, int* __restrict__ bucket) {
  if (threadIdx.x == 0) {
    int r = 0, nt = 0;
    for (int e = 0; e < NE; ++e) {
      meta[MI_POFF + e] = r;
      const int cnt = meta[MI_COUNTS + e];
      const int T = (cnt + BM - 1) / BM;
      for (int j = 0; j < T; ++j) {
        meta[MI_TILEE + nt] = e;
        meta[MI_TILER + nt] = r + j * BM;
        meta[MI_TILES0 + nt] = j * BM;
        ++nt;
      }
      r += T * BM;
    }
    meta[MI_POFF + NE] = r;
    meta[MI_NTILES] = nt;
  }
  __syncthreads();
  for (int e = 0; e < NE; ++e) {
    const int cnt = meta[MI_COUNTS + e];
    if (cnt == 0) continue;
    const int padTo = ((cnt + BM - 1) / BM) * BM;
    const int last = bucket[e * NT + cnt - 1];
    for (int i = cnt + threadIdx.x; i < padTo; i += blockDim.x)
      bucket[e * NT + i] = last;
  }
}

// ---------------------------------------------------------------------------
// gemm1 body with IN-KERNEL w1 conversion (fp32 B direct — kills cw1):
// A (bf16 xb, bucket-gathered) via global_load_lds into As[2][128][32].
// B (fp32 w1 [K][N]) via r1-proven staging: 16 coalesced dword loads/thread
// (reg-prefetched one K-step ahead), cvt, 4 ushort4 transposed writes into
// Bs[2][128][BKP=40]. 2 barriers per K-step. Out: relu(+b1) -> h bf16.
// ---------------------------------------------------------------------------
static __device__ __forceinline__ void gemm1_body_f32b(
    char* smem, int b, const __hip_bfloat16* __restrict__ A,
    const float* __restrict__ w1, const float* __restrict__ biasAll,
    const int* __restrict__ meta, const int* __restrict__ bucket,
    __hip_bfloat16* __restrict__ Hout) {
  auto As = reinterpret_cast<__hip_bfloat16(*)[BM][BK]>(smem);
  auto Bs = reinterpret_cast<__hip_bfloat16(*)[BN][BKP]>(smem + 16384);

  const int xcd = b & 7;
  const int idx = b >> 3;
  const int grp = idx / MAXT;        // 0..3
  const int tile = idx - grp * MAXT;
  const int ntile = xcd * 4 + grp;   // 32 ntiles, 4 per XCD
  if (tile >= meta[MI_NTILES]) return;

  const int e = meta[MI_TILEE + tile];
  const int row0 = meta[MI_TILER + tile];
  const int s0 = meta[MI_TILES0 + tile];
  const int n0 = ntile * BN;

  const int tid = threadIdx.x;
  const int lane = tid & 63;
  const int wid = tid >> 6;
  const int lr = lane >> 2, lc = lane & 3;

  const __hip_bfloat16* aP0 =
      A + (size_t)bucket[e * NT + s0 + 32 * wid + lr] * DM + lc * 8;
  const __hip_bfloat16* aP1 =
      A + (size_t)bucket[e * NT + s0 + 32 * wid + 16 + lr] * DM + lc * 8;

  // B staging: thread covers cols {bc,bc+32,bc+64,bc+96} x k-rows bk0..bk0+3
  const int bc = tid & 31;
  const int bk0 = (tid >> 5) * 4;
  const float* Bp = w1 + (size_t)e * DM * DH + n0 + bc;

  const int wm = (wid >> 1) * 64, wn = (wid & 1) * 64;
  const int fr = lane & 15, ks = lane >> 4;

  f32x4 acc[4][4];
#pragma unroll
  for (int m = 0; m < 4; ++m)
#pragma unroll
    for (int n = 0; n < 4; ++n) acc[m][n] = (f32x4){0.f, 0.f, 0.f, 0.f};

  float rb[4][4];  // [k-sub][col-group] for tile being prefetched

#define BLOAD(kt)                                                     \
  do {                                                                \
    const float* bbase = Bp + (size_t)((kt) * BK + bk0) * DH;         \
    _Pragma("unroll") for (int i = 0; i < 4; ++i)                     \
        _Pragma("unroll") for (int j = 0; j < 4; ++j)                 \
            rb[i][j] = bbase[(size_t)i * DH + 32 * j];                \
  } while (0)

#define BWRITE(bf)                                                    \
  do {                                                                \
    _Pragma("unroll") for (int j = 0; j < 4; ++j) {                   \
      ushort4 w;                                                      \
      w.x = f2bf(rb[0][j]); w.y = f2bf(rb[1][j]);                     \
      w.z = f2bf(rb[2][j]); w.w = f2bf(rb[3][j]);                     \
      *(ushort4*)&Bs[bf][bc + 32 * j][bk0] = w;                       \
    }                                                                 \
  } while (0)

#define ASTAGE(bf, kt)                                                \
  do {                                                                \
    gload16(aP0 + (size_t)(kt) * BK, &As[bf][32 * wid][0]);           \
    gload16(aP1 + (size_t)(kt) * BK, &As[bf][32 * wid + 16][0]);      \
  } while (0)

  // prologue
  BLOAD(0);
  ASTAGE(0, 0);
  BWRITE(0);
  if (1 < 32) BLOAD(1);
  __syncthreads();  // drains A(0) gl_lds; Bs[0] visible

  for (int kt = 0; kt < 32; ++kt) {
    const int buf = kt & 1;
    if (kt + 1 < 32) ASTAGE(buf ^ 1, kt + 1);  // flies under MFMAs
    bf16x8 afr[4], bfr[4];
#pragma unroll
    for (int m = 0; m < 4; ++m)
      afr[m] = *(const bf16x8*)&As[buf][wm + m * 16 + fr][ks * 8];
#pragma unroll
    for (int n = 0; n < 4; ++n)
      bfr[n] = *(const bf16x8*)&Bs[buf][wn + n * 16 + fr][ks * 8];
#pragma unroll
    for (int m = 0; m < 4; ++m)
#pragma unroll
      for (int n = 0; n < 4; ++n)
        acc[m][n] = __builtin_amdgcn_mfma_f32_16x16x32_bf16(afr[m], bfr[n],
                                                            acc[m][n], 0, 0, 0);
    __syncthreads();  // readers of buf done; A(kt+1) drained
    if (kt + 1 < 32) {
      BWRITE(buf ^ 1);            // tile kt+1 from prefetched rb
      if (kt + 2 < 32) BLOAD(kt + 2);  // prefetch next (covers next COMPUTE)
      __syncthreads();            // Bs[buf^1] visible
    }
  }
#undef BLOAD
#undef BWRITE
#undef ASTAGE

  const float* bias = biasAll + (size_t)e * DH;
#pragma unroll
  for (int m = 0; m < 4; ++m)
#pragma unroll
    for (int r = 0; r < 4; ++r) {
      const int row = wm + m * 16 + ks * 4 + r;
      __hip_bfloat16* orow = Hout + (size_t)(row0 + row) * DH;
#pragma unroll
      for (int n = 0; n < 4; ++n) {
        const int col = n0 + wn + n * 16 + fr;
        float v = acc[m][n][r] + bias[col];
        orow[col] = __float2bfloat16(v > 0.f ? v : 0.f);
      }
    }
}

// ---------------------------------------------------------------------------
// gemm2 body (unchanged r13): tiled bf16 w2t, gl_lds both operands, split-K.
// ---------------------------------------------------------------------------
static __device__ __forceinline__ void gemm2_body(
    char* smem, int b, const __hip_bfloat16* __restrict__ A,
    const __hip_bfloat16* __restrict__ B, const int* __restrict__ meta,
    float* __restrict__ Pout0) {
  auto As = reinterpret_cast<__hip_bfloat16(*)[BM][BK]>(smem);
  auto Bs = reinterpret_cast<__hip_bfloat16(*)[BN][BK]>(smem + 16384);

  const int xcd = b & 7;
  const int idx = b >> 3;
  const int grp = idx / MAXT;
  const int tile = idx - grp * MAXT;
  const int np = xcd * 2 + grp;      // 16 (ntile,kq) pairs, 2 per XCD
  const int ntile = np >> 1;
  const int kq = np & 1;
  if (tile >= meta[MI_NTILES]) return;

  const int e = meta[MI_TILEE + tile];
  const int row0 = meta[MI_TILER + tile];
  const int n0 = ntile * BN;
  const int kbase = kq * (DH / KSPL2);
  const int KTcnt = DH / 32;  // 128
  const int ktb = kq * 64;

  const int tid = threadIdx.x;
  const int lane = tid & 63;
  const int wid = tid >> 6;
  const int lr = lane >> 2, lc = lane & 3;

  const __hip_bfloat16* aP0 =
      A + (size_t)(row0 + 32 * wid + lr) * DH + kbase + lc * 8;
  const __hip_bfloat16* aP1 =
      A + (size_t)(row0 + 32 * wid + 16 + lr) * DH + kbase + lc * 8;
  const __hip_bfloat16* bP0 =
      B + (((size_t)e * (DM / 128) + ntile) * KTcnt + ktb) * 4096 +
      wid * 1024 + lane * 8;
  const __hip_bfloat16* bP1 = bP0 + 512;

  const int wm = (wid >> 1) * 64, wn = (wid & 1) * 64;
  const int fr = lane & 15, ks = lane >> 4;

  f32x4 acc[4][4];
#pragma unroll
  for (int m = 0; m < 4; ++m)
#pragma unroll
    for (int n = 0; n < 4; ++n) acc[m][n] = (f32x4){0.f, 0.f, 0.f, 0.f};

#define STAGE(bf, kt)                                              \
  do {                                                             \
    gload16(aP0 + (size_t)(kt) * BK, &As[bf][32 * wid][0]);        \
    gload16(aP1 + (size_t)(kt) * BK, &As[bf][32 * wid + 16][0]);   \
    gload16(bP0 + (size_t)(kt) * 4096, &Bs[bf][32 * wid][0]);      \
    gload16(bP1 + (size_t)(kt) * 4096, &Bs[bf][32 * wid + 16][0]); \
  } while (0)

  STAGE(0, 0);
  __syncthreads();

  for (int kt = 0; kt < 64; ++kt) {
    const int buf = kt & 1;
    if (kt + 1 < 64) STAGE(buf ^ 1, kt + 1);
    bf16x8 afr[4], bfr[4];
#pragma unroll
    for (int m = 0; m < 4; ++m)
      afr[m] = *(const bf16x8*)&As[buf][wm + m * 16 + fr][ks * 8];
#pragma unroll
    for (int n = 0; n < 4; ++n)
      bfr[n] = *(const bf16x8*)&Bs[buf][wn + n * 16 + fr][ks * 8];
#pragma unroll
    for (int m = 0; m < 4; ++m)
#pragma unroll
      for (int n = 0; n < 4; ++n)
        acc[m][n] = __builtin_amdgcn_mfma_f32_16x16x32_bf16(afr[m], bfr[n],
                                                            acc[m][n], 0, 0, 0);
    __syncthreads();
  }
#undef STAGE

  float* Pout = Pout0 + (size_t)kq * MAXROWS * DM;
#pragma unroll
  for (int m = 0; m < 4; ++m)
#pragma unroll
    for (int r = 0; r < 4; ++r) {
      const int row = wm + m * 16 + ks * 4 + r;
      float* orow = Pout + (size_t)(row0 + row) * DM;
#pragma unroll
      for (int n = 0; n < 4; ++n) {
        const int col = n0 + wn + n * 16 + fr;
        orow[col] = acc[m][n][r];
      }
    }
}

// ---------------------------------------------------------------------------
// Kernel: gemm1 fp32-B (blocks 0..G1B-1) + convert w2 tiled (G1B..+8191).
// ---------------------------------------------------------------------------
__global__ __launch_bounds__(256, 2) void gemm1f_cw2_kernel(
    const __hip_bfloat16* __restrict__ xb, const float* __restrict__ w1,
    const float* __restrict__ b1, const int* __restrict__ meta,
    const int* __restrict__ bucket, __hip_bfloat16* __restrict__ h,
    const float* __restrict__ w2, __hip_bfloat16* __restrict__ w2t) {
  __shared__ __align__(16) char smem[36864];  // As 16K + Bs 2*128*40*2=20.5K
  const int bid = blockIdx.x;
  if (bid < G1B) {
    gemm1_body_f32b(smem, bid, xb, w1, b1, meta, bucket, h);
    return;
  }
  const int id = bid - G1B;
  const int e = id >> 10;
  const int rem = id & 1023;           // 64 kg x 16 ng
  const int kglob0 = (rem >> 4) * 64;  // k slowest
  const int nglob0 = (rem & 15) * 64;  // n fastest
  convert_v4(w2 + (size_t)e * DH * DM, w2t + (size_t)e * DH * DM, DM,
             DH / 32, kglob0, nglob0, smem);
}

__global__ __launch_bounds__(256, 2) void gemm2_kernel(
    const __hip_bfloat16* __restrict__ h, const __hip_bfloat16* __restrict__ w2t,
    const int* __restrict__ meta, float* __restrict__ P) {
  __shared__ __align__(16) char smem[32768];
  gemm2_body(smem, blockIdx.x, h, w2t, meta, P);
}

// ---------------------------------------------------------------------------
// Reduce split-K partials, add b2, scatter padded-row -> token.
// ---------------------------------------------------------------------------
__global__ __launch_bounds__(256) void reduce_out_kernel(
    const float* __restrict__ P, const float* __restrict__ b2,
    const int* __restrict__ meta, const int* __restrict__ bucket,
    float* __restrict__ out) {
  const int gs = blockIdx.x;
  if (gs >= meta[MI_POFF + NE]) return;
  int e = 0;
#pragma unroll
  for (int i = 1; i < NE; ++i) e = (gs >= meta[MI_POFF + i]) ? i : e;
  const int i = gs - meta[MI_POFF + e];
  if (i >= meta[MI_COUNTS + e]) return;  // pad row
  const int tok = bucket[e * NT + i];
  const int c = threadIdx.x * 4;
  float4 v = *(const float4*)(P + (size_t)gs * DM + c);
#pragma unroll
  for (int q = 1; q < KSPL2; ++q) {
    float4 p = *(const float4*)(P + ((size_t)q * MAXROWS + gs) * DM + c);
    v.x += p.x; v.y += p.y; v.z += p.z; v.w += p.w;
  }
  float4 b = *(const float4*)(b2 + (size_t)e * DM + c);
  v.x += b.x; v.y += b.y; v.z += b.z; v.w += b.w;
  *(float4*)(out + (size_t)tok * DM + c) = v;
}

// ---------------------------------------------------------------------------
// Fallback path (small ws): round-1 proven kernels (raw fp32 weights).
// ---------------------------------------------------------------------------
template <bool RELU_BF16>
__global__ __launch_bounds__(256, 2) void moe_gemm_fallback(
    const __hip_bfloat16* __restrict__ Aall, int lda,
    const float* __restrict__ Ball, int K, int N,
    const float* __restrict__ biasAll, const int* __restrict__ counts,
    const int* __restrict__ bucket, void* __restrict__ Out, int ldo) {
  const int e = blockIdx.z;
  const int cnt = counts[e];
  const int m0 = blockIdx.y * BM;
  if (m0 >= cnt) return;
  const int n0 = blockIdx.x * BN;

  const float* Bp = Ball + (size_t)e * K * N;
  const float* bias = biasAll + (size_t)e * N;
  const int* buck = bucket + e * NT;

  __shared__ __align__(16) __hip_bfloat16 As[2][BM][BKP];
  __shared__ __align__(16) __hip_bfloat16 Bs[2][BN][BKP];

  const int tid = threadIdx.x;
  const int lane = tid & 63;
  const int wid = tid >> 6;
  const int wm = (wid >> 1) * 64;
  const int wn = (wid & 1) * 64;
  const int fr = lane & 15;
  const int ks = lane >> 4;

  const int ar = tid >> 1;
  const int ah = tid & 1;
  const int atok = buck[min(m0 + ar, cnt - 1)];
  const __hip_bfloat16* aptr = Aall + (size_t)atok * lda + ah * 16;

  const int bc = tid & 31;
  const int bk0 = (tid >> 5) * 4;

  f32x4 acc[4][4];
#pragma unroll
  for (int m = 0; m < 4; ++m)
#pragma unroll
    for (int n = 0; n < 4; ++n) acc[m][n] = (f32x4){0.f, 0.f, 0.f, 0.f};

  const int KTf = K / BK;
  uint4 ra0, ra1;
  float rb[4][4];

  {
    const uint4* p = (const uint4*)(aptr);
    ra0 = p[0]; ra1 = p[1];
    const float* bbase = Bp + (size_t)bk0 * N + n0 + bc;
#pragma unroll
    for (int i = 0; i < 4; ++i)
#pragma unroll
      for (int j = 0; j < 4; ++j) rb[i][j] = bbase[(size_t)i * N + 32 * j];
  }
  {
    *(uint4*)&As[0][ar][ah * 16] = ra0;
    *(uint4*)&As[0][ar][ah * 16 + 8] = ra1;
#pragma unroll
    for (int j = 0; j < 4; ++j) {
      ushort4 w;
      w.x = f2bf(rb[0][j]); w.y = f2bf(rb[1][j]);
      w.z = f2bf(rb[2][j]); w.w = f2bf(rb[3][j]);
      *(ushort4*)&Bs[0][bc + 32 * j][bk0] = w;
    }
  }
  __syncthreads();

  for (int kt = 0; kt < KTf; ++kt) {
    const int buf = kt & 1;
    if (kt + 1 < KTf) {
      const uint4* p = (const uint4*)(aptr + (size_t)(kt + 1) * BK);
      ra0 = p[0]; ra1 = p[1];
      const float* bbase = Bp + (size_t)((kt + 1) * BK + bk0) * N + n0 + bc;
#pragma unroll
      for (int i = 0; i < 4; ++i)
#pragma unroll
        for (int j = 0; j < 4; ++j) rb[i][j] = bbase[(size_t)i * N + 32 * j];
    }

    bf16x8 afr[4], bfr[4];
#pragma unroll
    for (int m = 0; m < 4; ++m)
      afr[m] = *(const bf16x8*)&As[buf][wm + m * 16 + fr][ks * 8];
#pragma unroll
    for (int n = 0; n < 4; ++n)
      bfr[n] = *(const bf16x8*)&Bs[buf][wn + n * 16 + fr][ks * 8];
#pragma unroll
    for (int m = 0; m < 4; ++m)
#pragma unroll
      for (int n = 0; n < 4; ++n)
        acc[m][n] = __builtin_amdgcn_mfma_f32_16x16x32_bf16(afr[m], bfr[n],
                                                            acc[m][n], 0, 0, 0);

    __syncthreads();
    if (kt + 1 < KTf) {
      *(uint4*)&As[buf ^ 1][ar][ah * 16] = ra0;
      *(uint4*)&As[buf ^ 1][ar][ah * 16 + 8] = ra1;
#pragma unroll
      for (int j = 0; j < 4; ++j) {
        ushort4 w;
        w.x = f2bf(rb[0][j]); w.y = f2bf(rb[1][j]);
        w.z = f2bf(rb[2][j]); w.w = f2bf(rb[3][j]);
        *(ushort4*)&Bs[buf ^ 1][bc + 32 * j][bk0] = w;
      }
      __syncthreads();
    }
  }

  float* outF = (float*)Out;
  __hip_bfloat16* outB = (__hip_bfloat16*)Out;
#pragma unroll
  for (int m = 0; m < 4; ++m) {
#pragma unroll
    for (int r = 0; r < 4; ++r) {
      const int row = wm + m * 16 + ks * 4 + r;
      const int slot = m0 + row;
      if (slot < cnt) {
        const int tok = buck[slot];
#pragma unroll
        for (int n = 0; n < 4; ++n) {
          const int col = n0 + wn + n * 16 + fr;
          float v = acc[m][n][r] + bias[col];
          if (RELU_BF16) {
            v = v > 0.f ? v : 0.f;
            outB[(size_t)tok * ldo + col] = __float2bfloat16(v);
          } else {
            outF[(size_t)tok * ldo + col] = v;
          }
        }
      }
    }
  }
}

extern "C" void kernel_launch(void* const* d_in, const int* in_sizes, int n_in,
                              void* d_out, int out_size, void* d_ws,
                              size_t ws_size, hipStream_t stream) {
  const float* x = (const float*)d_in[0];
  const float* gw = (const float*)d_in[1];
  const float* gb = (const float*)d_in[2];
  const float* w1 = (const float*)d_in[3];
  const float* b1 = (const float*)d_in[4];
  const float* w2 = (const float*)d_in[5];
  const float* b2 = (const float*)d_in[6];
  (void)in_sizes; (void)n_in; (void)out_size;

  char* ws = (char*)d_ws;
  int* meta = (int*)ws;
  int* counts = meta + MI_COUNTS;
  int* bucket = (int*)(ws + O_BUCKET);
  __hip_bfloat16* xb = (__hip_bfloat16*)(ws + O_XB);
  __hip_bfloat16* h = (__hip_bfloat16*)(ws + O_H);

  hipMemsetAsync(ws, 0, 1024, stream);

  if (ws_size >= WS_NEED) {
    __hip_bfloat16* w2t = (__hip_bfloat16*)(ws + O_W2T);
    float* P = (float*)(ws + O_P);

    gate_route_kernel<<<NT / 4, 256, 0, stream>>>(x, gw, gb, counts, bucket,
                                                  xb);
    prefix_kernel<<<1, 256, 0, stream>>>(meta, bucket);
    gemm1f_cw2_kernel<<<G1B + 8192, 256, 0, stream>>>(
        xb, w1, b1, meta, bucket, h, w2, w2t);
    gemm2_kernel<<<8 * 2 * MAXT, 256, 0, stream>>>(h, w2t, meta, P);
    reduce_out_kernel<<<MAXROWS, 256, 0, stream>>>(P, b2, meta, bucket,
                                                   (float*)d_out);
  } else {
    gate_route_kernel<<<NT / 4, 256, 0, stream>>>(x, gw, gb, counts, bucket,
                                                  xb);
    dim3 g1(DH / BN, NT / BM, NE);
    moe_gemm_fallback<true><<<g1, 256, 0, stream>>>(
        xb, DM, w1, DM, DH, b1, counts, bucket, (void*)h, DH);
    dim3 g2(DM / BN, NT / BM, NE);
    moe_gemm_fallback<false><<<g2, 256, 0, stream>>>(
        h, DH, w2, DH, DM, b2, counts, bucket, d_out, DM);
  }
}